// Round 3
// baseline (18.436 us; speedup 1.0000x reference)
//
#include <hip/hip_runtime.h>

#define TD 512    // teacher dim (K)
#define SD 128    // student dim (N)
#define NT 8      // n tasks
#define BATCH 16384
#define KC 128    // K-chunk staged in LDS

typedef float f32x4 __attribute__((ext_vector_type(4)));
typedef short s16x8 __attribute__((ext_vector_type(8)));

__device__ inline unsigned short f2bf_rne(float f) {
    unsigned int u = __builtin_bit_cast(unsigned int, f);
    unsigned int r = u + 0x7fffu + ((u >> 16) & 1u);
    return (unsigned short)(r >> 16);
}

// One fused kernel. Block = 256 threads (4 waves), 64 batch rows per block,
// grid = 256 blocks. Each wave computes a 16x128 output tile with
// mfma_f32_16x16x32_bf16. W is staged f32->bf16 into LDS per K-chunk,
// stored as Wt[n][k_local] (n-major) with XOR swizzle byte ^= (n&7)<<4.
__global__ __launch_bounds__(256) void fused_kernel(
    const float* __restrict__ emb,            // [500000][512]
    const float* __restrict__ clogits,        // [500000][8]
    const float* __restrict__ W,              // [512][128]
    const int* __restrict__ slot,             // [16384]
    const int* __restrict__ hit,              // [16384] int32 (bool -> int)
    float* __restrict__ feats_out,            // [16384][128]
    float* __restrict__ logits_out)           // [16384][8]
{
    __shared__ unsigned short Wt[SD * KC];    // 32 KiB, swizzled layout

    const int tid = threadIdx.x;
    const int m0b = blockIdx.x * 64;

    // ---- logits for this block's 64 rows (512 elems, 2 per thread) ----
    #pragma unroll
    for (int i = 0; i < 2; ++i) {
        int e = i * 256 + tid;
        int row = m0b + (e >> 3);
        int j = e & 7;
        float v = 0.f;
        if (hit[row]) v = clogits[(long)slot[row] * NT + j];
        logits_out[(long)row * NT + j] = v;
    }

    // ---- per-lane GEMM identity ----
    const int wave = tid >> 6;
    const int lane = tid & 63;
    const int lr = lane & 15;      // A row / B col / D col within tile
    const int kb = lane >> 4;      // k-octet index 0..3
    const int m0 = m0b + wave * 16;

    const int arow_idx = m0 + lr;
    const long myslot = slot[arow_idx];
    const bool myhit = hit[arow_idx] != 0;
    const float* arow = emb + myslot * (long)TD;

    // ---- staging identity: thread owns column n=sn, k-half skg ----
    const int sn  = tid & 127;     // 0..127
    const int skg = tid >> 7;      // 0..1 -> k_local in [skg*64, skg*64+64)

    f32x4 acc[8];
    #pragma unroll
    for (int t = 0; t < 8; ++t) acc[t] = (f32x4){0.f, 0.f, 0.f, 0.f};

    char* const wt_base = (char*)&Wt[0];

    for (int chunk = 0; chunk < 4; ++chunk) {
        const int kc0 = chunk * KC;

        // hoist this chunk's A-gather loads (overlap with staging below)
        f32x4 af[8];
        if (myhit) {
            #pragma unroll
            for (int ks = 0; ks < 4; ++ks) {
                const int kgo = kc0 + ks * 32 + kb * 8;
                af[2 * ks]     = *(const f32x4*)(arow + kgo);
                af[2 * ks + 1] = *(const f32x4*)(arow + kgo + 4);
            }
        }

        __syncthreads();   // previous chunk's LDS reads complete

        // ---- stage W chunk: Wt[n=sn][kl], kl = skg*64 .. +64 ----
        #pragma unroll
        for (int q = 0; q < 16; ++q) {
            const int kl = skg * 64 + q * 4;
            const int kg = kc0 + kl;
            unsigned short b4[4];
            #pragma unroll
            for (int ii = 0; ii < 4; ++ii)
                b4[ii] = f2bf_rne(W[(long)(kg + ii) * SD + sn]);
            const int byte_off = ((sn * KC + kl) * 2) ^ ((sn & 7) << 4);
            *(unsigned long long*)(wt_base + byte_off) =
                __builtin_bit_cast(unsigned long long,
                    (ushort4){b4[0], b4[1], b4[2], b4[3]});
        }

        __syncthreads();

        // ---- convert A and run MFMAs over this chunk ----
        #pragma unroll
        for (int ks = 0; ks < 4; ++ks) {
            s16x8 a;
            if (myhit) {
                const f32x4 f0 = af[2 * ks];
                const f32x4 f1 = af[2 * ks + 1];
                #pragma unroll
                for (int j = 0; j < 4; ++j) a[j]     = (short)f2bf_rne(f0[j]);
                #pragma unroll
                for (int j = 0; j < 4; ++j) a[4 + j] = (short)f2bf_rne(f1[j]);
            } else {
                a = (s16x8){0, 0, 0, 0, 0, 0, 0, 0};
            }
            const int klo = ks * 32 + kb * 8;     // k_local octet base
            #pragma unroll
            for (int t = 0; t < 8; ++t) {
                const int n = t * 16 + lr;
                const int boff = ((n * KC + klo) * 2) ^ ((n & 7) << 4);
                const s16x8 b = *(const s16x8*)(wt_base + boff);
                acc[t] = __builtin_amdgcn_mfma_f32_16x16x32_bf16(a, b, acc[t], 0, 0, 0);
            }
        }
    }

    // ---- write feats: D row = kb*4 + r (M index), col = t*16 + lr (N) ----
    #pragma unroll
    for (int t = 0; t < 8; ++t) {
        #pragma unroll
        for (int r = 0; r < 4; ++r) {
            const int orow = m0 + kb * 4 + r;
            const int ocol = t * 16 + lr;
            feats_out[(long)orow * SD + ocol] = acc[t][r];
        }
    }
}

extern "C" void kernel_launch(void* const* d_in, const int* in_sizes, int n_in,
                              void* d_out, int out_size, void* d_ws, size_t ws_size,
                              hipStream_t stream) {
    const float* cache_emb    = (const float*)d_in[0];
    const float* cache_logits = (const float*)d_in[1];
    const float* W            = (const float*)d_in[2];
    const int*   slot_idx     = (const int*)d_in[3];
    const int*   hitm         = (const int*)d_in[4];

    float* feats_out  = (float*)d_out;                       // 16384*128
    float* logits_out = (float*)d_out + (long)BATCH * SD;    // 16384*8

    fused_kernel<<<BATCH / 64, 256, 0, stream>>>(cache_emb, cache_logits, W,
                                                 slot_idx, hitm,
                                                 feats_out, logits_out);
}